// Round 12
// baseline (4729.016 us; speedup 1.0000x reference)
//
#include <hip/hip_runtime.h>
#include <math.h>

// Problem constants
#define BATCH 32
#define SEQ 256
#define EMBD 256
#define HDIM 256          // per-direction hidden
#define G4H 1024          // 4*H gates per direction
#define TAGS 12
#define START_IDX 10
#define STOP_IDX 11
#define NEGV -10000.0f

// lstm_rec: 4 WGs per (batch,dir) chain, 64 units/WG, 512 thr = 2 thr/row,
// each thread owns a K-half of 128 — now FULLY ON-CHIP (zero streamed tier):
//   k_local [0,56)   : VGPR (14 float4; live ~78 regs, budget 128 at 512 thr)
//   k_local [56,128) : LDS (18 float4 groups, 147,456 B staged once)
// K-loop touches no global memory -> isolates the per-step sync cost that
// round-11 exposed (13.4k cyc/step with only ~3k of VALU+stream).
// Critical-path trims vs round-11: 3 barriers/step (xval folded into part[]),
// h_all HBM store moved after the flag release, relaxed polling + one fence.
#define KRES 56
#define KLDS_G 18

// ---------------- Workspace layout (floats) ----------------
// xg     : [2][8192][1024]            = 16,777,216
// x      : [8192][256]                =  2,097,152   (dead after gemm_xg;
//           hx (64*512) + flags (64*4) live at its start during lstm_rec)
// h_all  : [32][256][512]             =  4,194,304
// feats  : [32][256][12]              =     98,304
#define WS_XG    0
#define WS_X     16777216
#define WS_HALL  19234816
#define WS_FEATS 23429120

// broadcast h[k] from lane-distributed VGPR (compile-time lane index)
__device__ __forceinline__ float bcast(float v, int l) {
    return __int_as_float(__builtin_amdgcn_readlane(__float_as_int(v), l));
}

// ---------------- Kernel 1: gather embeddings ----------------
__global__ void gather_x(const int* __restrict__ sent, const float* __restrict__ emb,
                         float* __restrict__ x) {
    int m = blockIdx.x;            // 8192 positions (b*256+s)
    int lane = threadIdx.x;        // 64
    long long row = sent[m];
    float4 v = *(const float4*)(emb + row * EMBD + lane * 4);
    *(float4*)(x + (size_t)m * EMBD + lane * 4) = v;
}

// ---------------- Kernel 2: xg GEMM  C[8192][2048] ----------------
__launch_bounds__(256)
__global__ void gemm_xg(const float* __restrict__ x,
                        const float* __restrict__ wih_f, const float* __restrict__ wih_b,
                        const float* __restrict__ bih_f, const float* __restrict__ bhh_f,
                        const float* __restrict__ bih_b, const float* __restrict__ bhh_b,
                        float* __restrict__ xg) {
    __shared__ __align__(16) float as[8][128];
    __shared__ __align__(16) float bs[8][128];
    int m0 = blockIdx.x * 128;     // 64 tiles
    int n0 = blockIdx.y * 128;     // 16 tiles
    int tid = threadIdx.x;
    int tx = tid & 15, ty = tid >> 4;
    int lr = tid >> 1;             // 0..127 tile row
    int lh = (tid & 1) * 4;        // k offset 0 or 4

    const float* arow = x + (size_t)(m0 + lr) * EMBD;
    const float* brow;
    {
        int n = n0 + lr;
        const float* w = (n < G4H) ? wih_f : wih_b;
        brow = w + (size_t)(n & 1023) * EMBD;
    }

    float acc[8][8];
    #pragma unroll
    for (int i = 0; i < 8; i++)
        #pragma unroll
        for (int j = 0; j < 8; j++) acc[i][j] = 0.f;

    for (int k0 = 0; k0 < EMBD; k0 += 8) {
        float4 av = *(const float4*)(arow + k0 + lh);
        float4 bv = *(const float4*)(brow + k0 + lh);
        __syncthreads();
        as[lh + 0][lr] = av.x; as[lh + 1][lr] = av.y; as[lh + 2][lr] = av.z; as[lh + 3][lr] = av.w;
        bs[lh + 0][lr] = bv.x; bs[lh + 1][lr] = bv.y; bs[lh + 2][lr] = bv.z; bs[lh + 3][lr] = bv.w;
        __syncthreads();
        #pragma unroll
        for (int kk = 0; kk < 8; kk++) {
            float4 a0 = *(const float4*)&as[kk][ty * 8];
            float4 a1 = *(const float4*)&as[kk][ty * 8 + 4];
            float4 b0 = *(const float4*)&bs[kk][tx * 8];
            float4 b1 = *(const float4*)&bs[kk][tx * 8 + 4];
            float a[8] = {a0.x, a0.y, a0.z, a0.w, a1.x, a1.y, a1.z, a1.w};
            float b[8] = {b0.x, b0.y, b0.z, b0.w, b1.x, b1.y, b1.z, b1.w};
            #pragma unroll
            for (int i = 0; i < 8; i++)
                #pragma unroll
                for (int j = 0; j < 8; j++) acc[i][j] += a[i] * b[j];
        }
    }

    int n = n0 + tx * 8;                 // tile stays within one dir (1024 % 128 == 0)
    int dir = n >> 10, g0 = n & 1023;
    const float* bih = dir ? bih_b : bih_f;
    const float* bhh = dir ? bhh_b : bhh_f;
    float bi[8], bh[8];
    #pragma unroll
    for (int j = 0; j < 8; j++) { bi[j] = bih[g0 + j]; bh[j] = bhh[g0 + j]; }
    float* ob = xg + (size_t)dir * 8192 * G4H;
    #pragma unroll
    for (int i = 0; i < 8; i++) {
        int m = m0 + ty * 8 + i;
        float v[8];
        #pragma unroll
        for (int j = 0; j < 8; j++) v[j] = (acc[i][j] + bi[j]) + bh[j];
        *(float4*)(ob + (size_t)m * G4H + g0)     = make_float4(v[0], v[1], v[2], v[3]);
        *(float4*)(ob + (size_t)m * G4H + g0 + 4) = make_float4(v[4], v[5], v[6], v[7]);
    }
}

// ---------------- Kernel 2b: zero sync state (every launch, after gemm) ----
__global__ void zero_sync(float* __restrict__ hx, int* __restrict__ flags) {
    int i = blockIdx.x * 256 + threadIdx.x;
    if (i < 64 * 512) hx[i] = 0.f;
    if (i < 64 * 4) flags[i] = 0;
}

// ---------------- Kernel 3: LSTM recurrence (4 WGs per chain, on-chip W) ---
#define DOT4(W, KL)                                              \
    a0 += (W).x * bcast(hv[((KL) + 0) >> 6], ((KL) + 0) & 63);   \
    a1 += (W).y * bcast(hv[((KL) + 1) >> 6], ((KL) + 1) & 63);   \
    a2 += (W).z * bcast(hv[((KL) + 2) >> 6], ((KL) + 2) & 63);   \
    a3 += (W).w * bcast(hv[((KL) + 3) >> 6], ((KL) + 3) & 63);

__launch_bounds__(512)
__global__ void lstm_rec(const float* __restrict__ xg,
                         const float* __restrict__ whh_f, const float* __restrict__ whh_b,
                         float* __restrict__ h_all,
                         float* __restrict__ hx, int* __restrict__ flags) {
    int blk = blockIdx.x;            // 256
    int chain = blk & 63;            // same-XCD for all 4 quarters of a chain
    int q = blk >> 6;                // quarter 0..3
    int dir = chain & 1, b = chain >> 1;
    int g = threadIdx.x;             // 0..511
    int lane = g & 63;
    int r = g & 255;                 // gate row within WG
    int kh = g >> 8;                 // K-half 0/1
    int G = r >> 6, ul = r & 63;
    int R = G * 256 + q * 64 + ul;   // global gate row

    const float* whh = dir ? whh_b : whh_f;
    const float* wrow = whh + (size_t)R * HDIM + kh * 128;     // this thread's K-half
    const float* xgb = xg + (size_t)dir * 8192 * G4H + (size_t)b * SEQ * G4H + R;
    float* hxc = hx + chain * 512;   // [2 parity][256 units]
    int* fl = flags + chain * 4;

    __shared__ __align__(16) float4 wlds[KLDS_G * 512];   // 147,456 B
    __shared__ float part[512];                           //   2,048 B

    // one-time stages: LDS tier k_local = 56..127
    #pragma unroll
    for (int j = 0; j < KLDS_G; j++)
        wlds[j * 512 + g] = *(const float4*)(wrow + KRES + j * 4);
    // VGPR tier k_local = 0..55 (live set ~78 regs; 512-thr budget = 128)
    float4 wr[KRES / 4];
    #pragma unroll
    for (int i = 0; i < KRES / 4; i++)
        wr[i] = *(const float4*)(wrow + i * 4);

    float c = 0.f;
    __syncthreads();

    for (int t = 0; t < SEQ; t++) {
        int s = dir ? (SEQ - 1 - t) : t;

        // h-independent long-latency load first (HBM xg stream)
        float xval = 0.f;
        if (g < 256) xval = xgb[(size_t)s * G4H];     // wave-uniform branch

        // wait for the 3 partner quarters' h_{t-1}: relaxed spin + one fence
        if (t > 0) {
            if (g < 3) {
                int pq = g + (g >= q ? 1 : 0);
                while (__hip_atomic_load(fl + pq, __ATOMIC_RELAXED,
                                         __HIP_MEMORY_SCOPE_AGENT) < t) {}
            }
            __syncthreads();
            __builtin_amdgcn_fence(__ATOMIC_ACQUIRE, "agent");
        }

        // h_{t-1} at parity (t+1)&1 (zeroed for t=0); only this K-half's 128
        int rp = (t + 1) & 1;
        float hv[2];
        #pragma unroll
        for (int j = 0; j < 2; j++)
            hv[j] = __hip_atomic_load(hxc + rp * 256 + kh * 128 + j * 64 + lane,
                                      __ATOMIC_RELAXED, __HIP_MEMORY_SCOPE_AGENT);

        float a0 = 0.f, a1 = 0.f, a2 = 0.f, a3 = 0.f;

        // VGPR tier k_local = 0..55
        #pragma unroll
        for (int i = 0; i < KRES / 4; i++) {
            float4 w = wr[i];
            DOT4(w, i * 4)
        }
        // LDS tier k_local = 56..127
        #pragma unroll
        for (int j = 0; j < KLDS_G; j++) {
            float4 w = wlds[j * 512 + g];
            DOT4(w, KRES + j * 4)
        }

        // part[] carries xval for the kh=0 half -> activation can sum directly
        part[g] = (a0 + a1) + (a2 + a3) + xval;
        __syncthreads();
        float h = 0.f;
        if (g < 64) {                                   // wave 0: 64 units
            float gi = part[g]       + part[g + 256];
            float gf = part[g + 64]  + part[g + 320];
            float gg = part[g + 128] + part[g + 384];
            float go = part[g + 192] + part[g + 448];
            float si = 1.f / (1.f + expf(-gi));
            float sf = 1.f / (1.f + expf(-gf));
            float so = 1.f / (1.f + expf(-go));
            c = sf * c + si * tanhf(gg);
            h = so * tanhf(c);
            __hip_atomic_store(hxc + (t & 1) * 256 + q * 64 + g, h,
                               __ATOMIC_RELAXED, __HIP_MEMORY_SCOPE_AGENT);
        }
        __syncthreads();   // drains vmcnt: hx writes complete before flag
        if (g == 0)
            __hip_atomic_store(fl + q, t + 1,
                               __ATOMIC_RELEASE, __HIP_MEMORY_SCOPE_AGENT);
        // h_all store AFTER the flag: HBM-store latency overlaps partner work
        if (g < 64)
            h_all[((size_t)b * SEQ + s) * 512 + dir * HDIM + q * 64 + g] = h;
    }
}

// ---------------- Kernel 4: output projection (feats) ----------------
__global__ void feats_kernel(const float* __restrict__ h_all, const float* __restrict__ w_out,
                             const float* __restrict__ b_out, float* __restrict__ feats) {
    int p = blockIdx.x;            // 8192
    int lane = threadIdx.x;        // 64
    const float* h = h_all + (size_t)p * 512;
    for (int f = 0; f < TAGS; f++) {
        float s = 0.f;
        const float* w = w_out + f * 512;
        #pragma unroll
        for (int k = 0; k < 512; k += 64) s += h[k + lane] * w[k + lane];
        #pragma unroll
        for (int off = 32; off; off >>= 1) s += __shfl_down(s, off);
        if (lane == 0) feats[(size_t)p * TAGS + f] = s + b_out[f];
    }
}

// ---------------- Kernel 5: Viterbi decode ----------------
__global__ void viterbi_kernel(const float* __restrict__ feats, const float* __restrict__ trans,
                               float* __restrict__ out) {
    int b = blockIdx.x;            // 32
    int t = threadIdx.x;           // 64
    __shared__ float fv[TAGS], fvn[TAGS], tr[TAGS * TAGS];
    __shared__ int bp[SEQ][TAGS];  // 12 KB

    for (int i = t; i < TAGS * TAGS; i += 64) tr[i] = trans[i];
    if (t < TAGS) fv[t] = (t == START_IDX) ? 0.f : NEGV;
    __syncthreads();

    const float* fb = feats + (size_t)b * SEQ * TAGS;
    for (int s = 0; s < SEQ; s++) {
        if (t < TAGS) {
            float best = fv[0] + tr[t * TAGS + 0];
            int bi = 0;
            #pragma unroll
            for (int prev = 1; prev < TAGS; prev++) {
                float v = fv[prev] + tr[t * TAGS + prev];
                if (v > best) { best = v; bi = prev; }   // first-index argmax
            }
            bp[s][t] = bi;
            fvn[t] = best + fb[s * TAGS + t];
        }
        __syncthreads();
        if (t < TAGS) fv[t] = fvn[t];
        __syncthreads();
    }

    if (t == 0) {
        float best = fv[0] + tr[STOP_IDX * TAGS + 0];
        int bi = 0;
        #pragma unroll
        for (int p = 1; p < TAGS; p++) {
            float v = fv[p] + tr[STOP_IDX * TAGS + p];
            if (v > best) { best = v; bi = p; }
        }
        out[b] = best;                                   // score
        float* path = out + BATCH + (size_t)b * SEQ;
        int tag = bi;
        path[SEQ - 1] = (float)tag;
        for (int s = SEQ - 1; s >= 1; s--) {
            tag = bp[s][tag];
            path[s - 1] = (float)tag;
        }
    }
}

// ---------------- Launch ----------------
extern "C" void kernel_launch(void* const* d_in, const int* in_sizes, int n_in,
                              void* d_out, int out_size, void* d_ws, size_t ws_size,
                              hipStream_t stream) {
    const int*   sent  = (const int*)d_in[0];
    const float* emb   = (const float*)d_in[1];
    const float* wih_f = (const float*)d_in[2];
    const float* whh_f = (const float*)d_in[3];
    const float* bih_f = (const float*)d_in[4];
    const float* bhh_f = (const float*)d_in[5];
    const float* wih_b = (const float*)d_in[6];
    const float* whh_b = (const float*)d_in[7];
    const float* bih_b = (const float*)d_in[8];
    const float* bhh_b = (const float*)d_in[9];
    const float* w_out = (const float*)d_in[10];
    const float* b_out = (const float*)d_in[11];
    const float* trans = (const float*)d_in[12];
    float* ws    = (float*)d_ws;
    float* xg    = ws + WS_XG;
    float* x     = ws + WS_X;
    float* h_all = ws + WS_HALL;
    float* feats = ws + WS_FEATS;
    // sync state lives in the x region (dead after gemm_xg; zeroed after it)
    float* hx    = ws + WS_X;
    int*   flags = (int*)(ws + WS_X + 64 * 512);
    float* out   = (float*)d_out;

    gather_x<<<BATCH * SEQ, 64, 0, stream>>>(sent, emb, x);
    gemm_xg<<<dim3(64, 16), 256, 0, stream>>>(x, wih_f, wih_b, bih_f, bhh_f, bih_b, bhh_b, xg);
    zero_sync<<<128, 256, 0, stream>>>(hx, flags);
    lstm_rec<<<256, 512, 0, stream>>>(xg, whh_f, whh_b, h_all, hx, flags);
    feats_kernel<<<BATCH * SEQ, 64, 0, stream>>>(h_all, w_out, b_out, feats);
    viterbi_kernel<<<BATCH, 64, 0, stream>>>(feats, trans, out);
}

// Round 13
// 1593.442 us; speedup vs baseline: 2.9678x; 2.9678x over previous
//
#include <hip/hip_runtime.h>
#include <math.h>

// Problem constants
#define BATCH 32
#define SEQ 256
#define EMBD 256
#define HDIM 256          // per-direction hidden
#define G4H 1024          // 4*H gates per direction
#define TAGS 12
#define START_IDX 10
#define STOP_IDX 11
#define NEGV -10000.0f

// lstm_rec: 2 WGs per (batch,dir) chain, split by hidden unit (128 units each).
// Per WG: 512 gate rows, K=256 dot. Weight tiers per row (R10 base, KRES 16->48):
//   k in [0,48)    : VGPR (12 float4; live ~87 regs, measured budget 128 @512thr)
//   k in [48,120)  : LDS (18 float4 groups, 147,456 B staged once)
//   k in [120,256) : streamed from L2 (34 float4 groups, depth-4 ring)
// Stream/WG/step = 272 KB (vs 344 KB in R10) -> shaves the dominant
// per-CU L1-return-bandwidth term (measured 5.4k of 12.1k cyc/step).
// Sync pattern IDENTICAL to the proven R10 kernel (acquire poll, no fence).
#define KRES 48
#define KLDS_G 18
#define KSTR_G 34

// ---------------- Workspace layout (floats) ----------------
// xg     : [2][8192][1024]            = 16,777,216
// x      : [8192][256]                =  2,097,152   (dead after gemm_xg;
//           hx (64*512) + flags (128) live at its start during lstm_rec)
// wpack  : [2][2][34][512] float4     =    278,528 floats
// h_all  : [32][256][512]             =  4,194,304
// feats  : [32][256][12]              =     98,304
#define WS_XG    0
#define WS_X     16777216
#define WS_WPACK 18874368
#define WS_HALL  19234816
#define WS_FEATS 23429120

// broadcast h[k] from lane-distributed VGPR (compile-time lane index)
__device__ __forceinline__ float bcast(float v, int l) {
    return __int_as_float(__builtin_amdgcn_readlane(__float_as_int(v), l));
}

// ---------------- Kernel 1: gather embeddings ----------------
__global__ void gather_x(const int* __restrict__ sent, const float* __restrict__ emb,
                         float* __restrict__ x) {
    int m = blockIdx.x;            // 8192 positions (b*256+s)
    int lane = threadIdx.x;        // 64
    long long row = sent[m];
    float4 v = *(const float4*)(emb + row * EMBD + lane * 4);
    *(float4*)(x + (size_t)m * EMBD + lane * 4) = v;
}

// ---------------- Kernel 2: pack streamed tail of whh ----------------
// wpack[((dir*2+half)*34+j)*512+g] = whh_dir[R(g,half)][120+4j .. +3]
// R(g,half) = (g>>7)*256 + half*128 + (g&127)
__global__ void pack_whh(const float* __restrict__ whh_f, const float* __restrict__ whh_b,
                         float4* __restrict__ pack) {
    int idx = blockIdx.x * 256 + threadIdx.x;      // 2*2*34*512 = 69632
    if (idx >= 2 * 2 * KSTR_G * 512) return;
    int g = idx & 511;
    int r = idx >> 9;
    int j = r % KSTR_G; r /= KSTR_G;
    int half = r & 1, dir = r >> 1;
    int R = (g >> 7) * 256 + half * 128 + (g & 127);
    const float* w = dir ? whh_b : whh_f;
    pack[idx] = *(const float4*)(w + (size_t)R * HDIM + KRES + 4 * KLDS_G + 4 * j);
}

// ---------------- Kernel 3: xg GEMM  C[8192][2048] ----------------
__launch_bounds__(256)
__global__ void gemm_xg(const float* __restrict__ x,
                        const float* __restrict__ wih_f, const float* __restrict__ wih_b,
                        const float* __restrict__ bih_f, const float* __restrict__ bhh_f,
                        const float* __restrict__ bih_b, const float* __restrict__ bhh_b,
                        float* __restrict__ xg) {
    __shared__ __align__(16) float as[8][128];
    __shared__ __align__(16) float bs[8][128];
    int m0 = blockIdx.x * 128;     // 64 tiles
    int n0 = blockIdx.y * 128;     // 16 tiles
    int tid = threadIdx.x;
    int tx = tid & 15, ty = tid >> 4;
    int lr = tid >> 1;             // 0..127 tile row
    int lh = (tid & 1) * 4;        // k offset 0 or 4

    const float* arow = x + (size_t)(m0 + lr) * EMBD;
    const float* brow;
    {
        int n = n0 + lr;
        const float* w = (n < G4H) ? wih_f : wih_b;
        brow = w + (size_t)(n & 1023) * EMBD;
    }

    float acc[8][8];
    #pragma unroll
    for (int i = 0; i < 8; i++)
        #pragma unroll
        for (int j = 0; j < 8; j++) acc[i][j] = 0.f;

    for (int k0 = 0; k0 < EMBD; k0 += 8) {
        float4 av = *(const float4*)(arow + k0 + lh);
        float4 bv = *(const float4*)(brow + k0 + lh);
        __syncthreads();
        as[lh + 0][lr] = av.x; as[lh + 1][lr] = av.y; as[lh + 2][lr] = av.z; as[lh + 3][lr] = av.w;
        bs[lh + 0][lr] = bv.x; bs[lh + 1][lr] = bv.y; bs[lh + 2][lr] = bv.z; bs[lh + 3][lr] = bv.w;
        __syncthreads();
        #pragma unroll
        for (int kk = 0; kk < 8; kk++) {
            float4 a0 = *(const float4*)&as[kk][ty * 8];
            float4 a1 = *(const float4*)&as[kk][ty * 8 + 4];
            float4 b0 = *(const float4*)&bs[kk][tx * 8];
            float4 b1 = *(const float4*)&bs[kk][tx * 8 + 4];
            float a[8] = {a0.x, a0.y, a0.z, a0.w, a1.x, a1.y, a1.z, a1.w};
            float b[8] = {b0.x, b0.y, b0.z, b0.w, b1.x, b1.y, b1.z, b1.w};
            #pragma unroll
            for (int i = 0; i < 8; i++)
                #pragma unroll
                for (int j = 0; j < 8; j++) acc[i][j] += a[i] * b[j];
        }
    }

    int n = n0 + tx * 8;                 // tile stays within one dir (1024 % 128 == 0)
    int dir = n >> 10, g0 = n & 1023;
    const float* bih = dir ? bih_b : bih_f;
    const float* bhh = dir ? bhh_b : bhh_f;
    float bi[8], bh[8];
    #pragma unroll
    for (int j = 0; j < 8; j++) { bi[j] = bih[g0 + j]; bh[j] = bhh[g0 + j]; }
    float* ob = xg + (size_t)dir * 8192 * G4H;
    #pragma unroll
    for (int i = 0; i < 8; i++) {
        int m = m0 + ty * 8 + i;
        float v[8];
        #pragma unroll
        for (int j = 0; j < 8; j++) v[j] = (acc[i][j] + bi[j]) + bh[j];
        *(float4*)(ob + (size_t)m * G4H + g0)     = make_float4(v[0], v[1], v[2], v[3]);
        *(float4*)(ob + (size_t)m * G4H + g0 + 4) = make_float4(v[4], v[5], v[6], v[7]);
    }
}

// ---------------- Kernel 3b: zero sync state (every launch, after gemm) ----
__global__ void zero_sync(float* __restrict__ hx, int* __restrict__ flags) {
    int i = blockIdx.x * 256 + threadIdx.x;
    if (i < 64 * 512) hx[i] = 0.f;
    if (i < 128) flags[i] = 0;
}

// ---------------- Kernel 4: LSTM recurrence (2 WGs per chain) -------------
#define DOT4(W, K)                                              \
    a0 += (W).x * bcast(hv[((K) + 0) >> 6], ((K) + 0) & 63);    \
    a1 += (W).y * bcast(hv[((K) + 1) >> 6], ((K) + 1) & 63);    \
    a2 += (W).z * bcast(hv[((K) + 2) >> 6], ((K) + 2) & 63);    \
    a3 += (W).w * bcast(hv[((K) + 3) >> 6], ((K) + 3) & 63);

__launch_bounds__(512)
__global__ void lstm_rec(const float* __restrict__ xg,
                         const float* __restrict__ whh_f, const float* __restrict__ whh_b,
                         const float4* __restrict__ wpack,
                         float* __restrict__ h_all,
                         float* __restrict__ hx, int* __restrict__ flags) {
    int blk = blockIdx.x;            // 128
    int half = blk & 1;
    int chain = blk >> 1;            // 64
    int dir = chain & 1, b = chain >> 1;
    int g = threadIdx.x;             // 0..511
    int lane = g & 63;
    int unit0 = half * 128;
    int R = (g >> 7) * 256 + unit0 + (g & 127);    // global gate row

    const float* whh = dir ? whh_b : whh_f;
    const float4* wp = wpack + (size_t)(dir * 2 + half) * KSTR_G * 512 + g;
    const float* xgb = xg + (size_t)dir * 8192 * G4H + (size_t)b * SEQ * G4H + R;
    float* hxc = hx + chain * 512;                 // [2 parity][256 units]
    int* own_flag = flags + chain * 2 + half;
    int* par_flag = flags + chain * 2 + (1 - half);

    __shared__ __align__(16) float4 wlds[KLDS_G * 512];   // 147,456 B
    __shared__ float gates[512];                          //   2,048 B

    // one-time stages
    #pragma unroll
    for (int j = 0; j < KLDS_G; j++)
        wlds[j * 512 + g] = *(const float4*)(whh + (size_t)R * HDIM + KRES + j * 4);
    float4 wr[KRES / 4];
    #pragma unroll
    for (int i = 0; i < KRES / 4; i++)
        wr[i] = *(const float4*)(whh + (size_t)R * HDIM + i * 4);

    float c = 0.f;
    __syncthreads();

    for (int t = 0; t < SEQ; t++) {
        int s = dir ? (SEQ - 1 - t) : t;

        // issue h-independent long-latency loads before the wait
        float xval = xgb[(size_t)s * G4H];
        float4 sb[4];
        #pragma unroll
        for (int p = 0; p < 4; p++) sb[p] = wp[(size_t)p * 512];

        // wait for partner's h_{t-1}
        if (t > 0) {
            if (g == 0)
                while (__hip_atomic_load(par_flag, __ATOMIC_ACQUIRE,
                                         __HIP_MEMORY_SCOPE_AGENT) < t) {}
            __syncthreads();
        }

        // h_{t-1} lives at parity (t-1)&1 == (t+1)&1 ; zeroed for t=0
        int rp = (t + 1) & 1;
        float hv[4];
        #pragma unroll
        for (int j = 0; j < 4; j++)
            hv[j] = __hip_atomic_load(hxc + rp * 256 + j * 64 + lane,
                                      __ATOMIC_RELAXED, __HIP_MEMORY_SCOPE_AGENT);

        float a0 = xval, a1 = 0.f, a2 = 0.f, a3 = 0.f;

        // VGPR tier k = 0..47
        #pragma unroll
        for (int i = 0; i < KRES / 4; i++) {
            float4 w = wr[i];
            DOT4(w, i * 4)
        }
        // LDS tier k = 48..119
        #pragma unroll
        for (int j = 0; j < KLDS_G; j++) {
            float4 w = wlds[j * 512 + g];
            DOT4(w, KRES + j * 4)
        }
        // streamed tier k = 120..255, depth-4 ring
        #pragma unroll
        for (int j = 0; j < KSTR_G; j++) {
            float4 w = sb[j & 3];
            if (j + 4 < KSTR_G) sb[j & 3] = wp[(size_t)(j + 4) * 512];
            DOT4(w, KRES + 4 * KLDS_G + j * 4)
        }

        gates[g] = (a0 + a1) + (a2 + a3);
        __syncthreads();
        if (g < 128) {
            float gi = gates[g], gf = gates[128 + g], gg = gates[256 + g], go = gates[384 + g];
            float si = 1.f / (1.f + expf(-gi));
            float sf = 1.f / (1.f + expf(-gf));
            float so = 1.f / (1.f + expf(-go));
            c = sf * c + si * tanhf(gg);
            float h = so * tanhf(c);
            int u = unit0 + g;
            h_all[((size_t)b * SEQ + s) * 512 + dir * HDIM + u] = h;
            __hip_atomic_store(hxc + (t & 1) * 256 + u, h,
                               __ATOMIC_RELAXED, __HIP_MEMORY_SCOPE_AGENT);
        }
        __syncthreads();   // drains vmcnt: hx writes complete before flag
        if (g == 0)
            __hip_atomic_store(own_flag, t + 1,
                               __ATOMIC_RELEASE, __HIP_MEMORY_SCOPE_AGENT);
    }
}

// ---------------- Kernel 5: output projection (feats) ----------------
__global__ void feats_kernel(const float* __restrict__ h_all, const float* __restrict__ w_out,
                             const float* __restrict__ b_out, float* __restrict__ feats) {
    int p = blockIdx.x;            // 8192
    int lane = threadIdx.x;        // 64
    const float* h = h_all + (size_t)p * 512;
    for (int f = 0; f < TAGS; f++) {
        float s = 0.f;
        const float* w = w_out + f * 512;
        #pragma unroll
        for (int k = 0; k < 512; k += 64) s += h[k + lane] * w[k + lane];
        #pragma unroll
        for (int off = 32; off; off >>= 1) s += __shfl_down(s, off);
        if (lane == 0) feats[(size_t)p * TAGS + f] = s + b_out[f];
    }
}

// ---------------- Kernel 6: Viterbi decode ----------------
__global__ void viterbi_kernel(const float* __restrict__ feats, const float* __restrict__ trans,
                               float* __restrict__ out) {
    int b = blockIdx.x;            // 32
    int t = threadIdx.x;           // 64
    __shared__ float fv[TAGS], fvn[TAGS], tr[TAGS * TAGS];
    __shared__ int bp[SEQ][TAGS];  // 12 KB

    for (int i = t; i < TAGS * TAGS; i += 64) tr[i] = trans[i];
    if (t < TAGS) fv[t] = (t == START_IDX) ? 0.f : NEGV;
    __syncthreads();

    const float* fb = feats + (size_t)b * SEQ * TAGS;
    for (int s = 0; s < SEQ; s++) {
        if (t < TAGS) {
            float best = fv[0] + tr[t * TAGS + 0];
            int bi = 0;
            #pragma unroll
            for (int prev = 1; prev < TAGS; prev++) {
                float v = fv[prev] + tr[t * TAGS + prev];
                if (v > best) { best = v; bi = prev; }   // first-index argmax
            }
            bp[s][t] = bi;
            fvn[t] = best + fb[s * TAGS + t];
        }
        __syncthreads();
        if (t < TAGS) fv[t] = fvn[t];
        __syncthreads();
    }

    if (t == 0) {
        float best = fv[0] + tr[STOP_IDX * TAGS + 0];
        int bi = 0;
        #pragma unroll
        for (int p = 1; p < TAGS; p++) {
            float v = fv[p] + tr[STOP_IDX * TAGS + p];
            if (v > best) { best = v; bi = p; }
        }
        out[b] = best;                                   // score
        float* path = out + BATCH + (size_t)b * SEQ;
        int tag = bi;
        path[SEQ - 1] = (float)tag;
        for (int s = SEQ - 1; s >= 1; s--) {
            tag = bp[s][tag];
            path[s - 1] = (float)tag;
        }
    }
}

// ---------------- Launch ----------------
extern "C" void kernel_launch(void* const* d_in, const int* in_sizes, int n_in,
                              void* d_out, int out_size, void* d_ws, size_t ws_size,
                              hipStream_t stream) {
    const int*   sent  = (const int*)d_in[0];
    const float* emb   = (const float*)d_in[1];
    const float* wih_f = (const float*)d_in[2];
    const float* whh_f = (const float*)d_in[3];
    const float* bih_f = (const float*)d_in[4];
    const float* bhh_f = (const float*)d_in[5];
    const float* wih_b = (const float*)d_in[6];
    const float* whh_b = (const float*)d_in[7];
    const float* bih_b = (const float*)d_in[8];
    const float* bhh_b = (const float*)d_in[9];
    const float* w_out = (const float*)d_in[10];
    const float* b_out = (const float*)d_in[11];
    const float* trans = (const float*)d_in[12];
    float* ws    = (float*)d_ws;
    float* xg    = ws + WS_XG;
    float* x     = ws + WS_X;
    float* wpack = ws + WS_WPACK;
    float* h_all = ws + WS_HALL;
    float* feats = ws + WS_FEATS;
    // sync state lives in the x region (dead after gemm_xg; zeroed after it)
    float* hx    = ws + WS_X;
    int*   flags = (int*)(ws + WS_X + 64 * 512);
    float* out   = (float*)d_out;

    gather_x<<<BATCH * SEQ, 64, 0, stream>>>(sent, emb, x);
    pack_whh<<<(2 * 2 * KSTR_G * 512 + 255) / 256, 256, 0, stream>>>(whh_f, whh_b, (float4*)wpack);
    gemm_xg<<<dim3(64, 16), 256, 0, stream>>>(x, wih_f, wih_b, bih_f, bhh_f, bih_b, bhh_b, xg);
    zero_sync<<<128, 256, 0, stream>>>(hx, flags);
    lstm_rec<<<128, 512, 0, stream>>>(xg, whh_f, whh_b, (const float4*)wpack, h_all, hx, flags);
    feats_kernel<<<BATCH * SEQ, 64, 0, stream>>>(h_all, w_out, b_out, feats);
    viterbi_kernel<<<BATCH, 64, 0, stream>>>(feats, trans, out);
}

// Round 16
// 1551.775 us; speedup vs baseline: 3.0475x; 1.0269x over previous
//
#include <hip/hip_runtime.h>
#include <math.h>

// Problem constants
#define BATCH 32
#define SEQ 256
#define EMBD 256
#define HDIM 256          // per-direction hidden
#define G4H 1024          // 4*H gates per direction
#define TAGS 12
#define START_IDX 10
#define STOP_IDX 11
#define NEGV -10000.0f

// lstm_rec: 2 WGs per (batch,dir) chain, 128 units each, 512 thr = 1 gate row
// per thread (R = (g>>7)*256 + unit0 + (g&127)).
// Phase-split dot (R14): own-half K (k in [o0,o0+128), h from LDS) is computed
// BEFORE the partner poll — its 32 streamed groups (8-deep ring) hide in the
// poll shadow. Partner-half K gets the on-chip tiers and runs after the poll:
//   partner k [p0,p0+48)    : VGPR (12 float4)
//   partner k [p0+48,p0+120): LDS  (18 groups, 147,456 B)
//   partner k [p0+120,+128) : 2 streamed groups, pre-issued at loop top
// Sync handshake byte-identical to R10/R13 (acquire poll by g==0, relaxed
// agent atomics for h, release flag) — R12 proved fences/bundles regress.
#define KV 48            // partner VGPR-tier k-count
#define KL_G 18          // partner LDS-tier float4 groups
#define PT_G 2           // partner streamed tail groups
#define OWN_G 32         // own-half streamed groups
#define KSTR_G 34        // total streamed groups (= PT_G + OWN_G)
#define RING 8

// ---------------- Workspace layout (floats) ----------------
// xg     : [2][8192][1024]            = 16,777,216
// x      : [8192][256]                =  2,097,152   (dead after gemm_xg;
//           hx (64*512) + flags (128) live at its start during lstm_rec)
// wpack  : [2][2][34][512] float4     =    278,528 floats
// h_all  : [32][256][512]             =  4,194,304
// feats  : [32][256][12]              =     98,304
#define WS_XG    0
#define WS_X     16777216
#define WS_WPACK 18874368
#define WS_HALL  19234816
#define WS_FEATS 23429120

// broadcast h[k] from lane-distributed VGPR (compile-time lane index)
__device__ __forceinline__ float bcast(float v, int l) {
    return __int_as_float(__builtin_amdgcn_readlane(__float_as_int(v), l));
}

// ---------------- Kernel 1: gather embeddings ----------------
__global__ void gather_x(const int* __restrict__ sent, const float* __restrict__ emb,
                         float* __restrict__ x) {
    int m = blockIdx.x;            // 8192 positions (b*256+s)
    int lane = threadIdx.x;        // 64
    long long row = sent[m];
    float4 v = *(const float4*)(emb + row * EMBD + lane * 4);
    *(float4*)(x + (size_t)m * EMBD + lane * 4) = v;
}

// ---------------- Kernel 2: pack streamed weights ----------------
// For WG (dir,half): own base o0 = half*128, partner base p0 = 128-o0.
// Group j<2  -> partner tail k = p0 + 120 + 4j
// Group j>=2 -> own        k = o0 + 4*(j-2)
// pack[(((dir*2+half)*34)+j)*512 + g] = whh_dir[R(g,half)][k .. k+3]
__global__ void pack_whh(const float* __restrict__ whh_f, const float* __restrict__ whh_b,
                         float4* __restrict__ pack) {
    int idx = blockIdx.x * 256 + threadIdx.x;      // 2*2*34*512 = 69632
    if (idx >= 2 * 2 * KSTR_G * 512) return;
    int g = idx & 511;
    int r = idx >> 9;
    int j = r % KSTR_G; r /= KSTR_G;
    int half = r & 1, dir = r >> 1;
    int o0 = half * 128, p0 = 128 - o0;
    int R = (g >> 7) * 256 + o0 + (g & 127);
    int k = (j < PT_G) ? (p0 + KV + 4 * KL_G + 4 * j) : (o0 + 4 * (j - PT_G));
    const float* w = dir ? whh_b : whh_f;
    pack[idx] = *(const float4*)(w + (size_t)R * HDIM + k);
}

// ---------------- Kernel 3: xg GEMM  C[8192][2048] ----------------
__launch_bounds__(256)
__global__ void gemm_xg(const float* __restrict__ x,
                        const float* __restrict__ wih_f, const float* __restrict__ wih_b,
                        const float* __restrict__ bih_f, const float* __restrict__ bhh_f,
                        const float* __restrict__ bih_b, const float* __restrict__ bhh_b,
                        float* __restrict__ xg) {
    __shared__ __align__(16) float as[8][128];
    __shared__ __align__(16) float bs[8][128];
    int m0 = blockIdx.x * 128;     // 64 tiles
    int n0 = blockIdx.y * 128;     // 16 tiles
    int tid = threadIdx.x;
    int tx = tid & 15, ty = tid >> 4;
    int lr = tid >> 1;             // 0..127 tile row
    int lh = (tid & 1) * 4;        // k offset 0 or 4

    const float* arow = x + (size_t)(m0 + lr) * EMBD;
    const float* brow;
    {
        int n = n0 + lr;
        const float* w = (n < G4H) ? wih_f : wih_b;
        brow = w + (size_t)(n & 1023) * EMBD;
    }

    float acc[8][8];
    #pragma unroll
    for (int i = 0; i < 8; i++)
        #pragma unroll
        for (int j = 0; j < 8; j++) acc[i][j] = 0.f;

    for (int k0 = 0; k0 < EMBD; k0 += 8) {
        float4 av = *(const float4*)(arow + k0 + lh);
        float4 bv = *(const float4*)(brow + k0 + lh);
        __syncthreads();
        as[lh + 0][lr] = av.x; as[lh + 1][lr] = av.y; as[lh + 2][lr] = av.z; as[lh + 3][lr] = av.w;
        bs[lh + 0][lr] = bv.x; bs[lh + 1][lr] = bv.y; bs[lh + 2][lr] = bv.z; bs[lh + 3][lr] = bv.w;
        __syncthreads();
        #pragma unroll
        for (int kk = 0; kk < 8; kk++) {
            float4 a0 = *(const float4*)&as[kk][ty * 8];
            float4 a1 = *(const float4*)&as[kk][ty * 8 + 4];
            float4 b0 = *(const float4*)&bs[kk][tx * 8];
            float4 b1 = *(const float4*)&bs[kk][tx * 8 + 4];
            float a[8] = {a0.x, a0.y, a0.z, a0.w, a1.x, a1.y, a1.z, a1.w};
            float b[8] = {b0.x, b0.y, b0.z, b0.w, b1.x, b1.y, b1.z, b1.w};
            #pragma unroll
            for (int i = 0; i < 8; i++)
                #pragma unroll
                for (int j = 0; j < 8; j++) acc[i][j] += a[i] * b[j];
        }
    }

    int n = n0 + tx * 8;                 // tile stays within one dir (1024 % 128 == 0)
    int dir = n >> 10, g0 = n & 1023;
    const float* bih = dir ? bih_b : bih_f;
    const float* bhh = dir ? bhh_b : bhh_f;
    float bi[8], bh[8];
    #pragma unroll
    for (int j = 0; j < 8; j++) { bi[j] = bih[g0 + j]; bh[j] = bhh[g0 + j]; }
    float* ob = xg + (size_t)dir * 8192 * G4H;
    #pragma unroll
    for (int i = 0; i < 8; i++) {
        int m = m0 + ty * 8 + i;
        float v[8];
        #pragma unroll
        for (int j = 0; j < 8; j++) v[j] = (acc[i][j] + bi[j]) + bh[j];
        *(float4*)(ob + (size_t)m * G4H + g0)     = make_float4(v[0], v[1], v[2], v[3]);
        *(float4*)(ob + (size_t)m * G4H + g0 + 4) = make_float4(v[4], v[5], v[6], v[7]);
    }
}

// ---------------- Kernel 3b: zero sync state (every launch, after gemm) ----
__global__ void zero_sync(float* __restrict__ hx, int* __restrict__ flags) {
    int i = blockIdx.x * 256 + threadIdx.x;
    if (i < 64 * 512) hx[i] = 0.f;
    if (i < 128) flags[i] = 0;
}

// ---------------- Kernel 4: LSTM recurrence (phase-split dot) -------------
#define DOT4(W, HV, KL)                                              \
    a0 += (W).x * bcast(HV[((KL) + 0) >> 6], ((KL) + 0) & 63);       \
    a1 += (W).y * bcast(HV[((KL) + 1) >> 6], ((KL) + 1) & 63);       \
    a2 += (W).z * bcast(HV[((KL) + 2) >> 6], ((KL) + 2) & 63);       \
    a3 += (W).w * bcast(HV[((KL) + 3) >> 6], ((KL) + 3) & 63);

__launch_bounds__(512)
__global__ void lstm_rec(const float* __restrict__ xg,
                         const float* __restrict__ whh_f, const float* __restrict__ whh_b,
                         const float4* __restrict__ wpack,
                         float* __restrict__ h_all,
                         float* __restrict__ hx, int* __restrict__ flags) {
    int blk = blockIdx.x;            // 128
    int half = blk & 1;
    int chain = blk >> 1;            // 64
    int dir = chain & 1, b = chain >> 1;
    int g = threadIdx.x;             // 0..511
    int lane = g & 63;
    int unit0 = half * 128;          // own base o0
    int p0 = 128 - unit0;            // partner base
    int R = (g >> 7) * 256 + unit0 + (g & 127);    // global gate row

    const float* whh = dir ? whh_b : whh_f;
    const float* wrow = whh + (size_t)R * HDIM;
    const float4* wp = wpack + (size_t)(dir * 2 + half) * KSTR_G * 512 + g;
    const float* xgb = xg + (size_t)dir * 8192 * G4H + (size_t)b * SEQ * G4H + R;
    float* hxc = hx + chain * 512;                 // [2 parity][256 units]
    int* own_flag = flags + chain * 2 + half;
    int* par_flag = flags + chain * 2 + (1 - half);

    __shared__ __align__(16) float4 wlds[KL_G * 512];     // 147,456 B
    __shared__ float gates[512];                          //   2,048 B
    __shared__ float h_own[128];                          //     512 B

    // one-time stages: partner-half on-chip tiers
    #pragma unroll
    for (int j = 0; j < KL_G; j++)
        wlds[j * 512 + g] = *(const float4*)(wrow + p0 + KV + j * 4);
    float4 wr[KV / 4];
    #pragma unroll
    for (int i = 0; i < KV / 4; i++)
        wr[i] = *(const float4*)(wrow + p0 + i * 4);

    float c = 0.f;
    if (g < 128) h_own[g] = 0.f;
    __syncthreads();

    for (int t = 0; t < SEQ; t++) {
        int s = dir ? (SEQ - 1 - t) : t;

        // pre-issue all h-independent long-latency loads
        float xval = xgb[(size_t)s * G4H];
        float4 sbB[2];                                   // partner streamed tail
        sbB[0] = wp[0 * 512]; sbB[1] = wp[1 * 512];
        float4 sb[RING];                                 // own ring, groups 2..9
        #pragma unroll
        for (int p = 0; p < RING; p++) sb[p] = wp[(size_t)(PT_G + p) * 512];

        // ---- phase A: own-half dot (h from LDS, no wait) ----
        float hvo[2];
        #pragma unroll
        for (int j = 0; j < 2; j++) hvo[j] = h_own[j * 64 + lane];

        float a0 = xval, a1 = 0.f, a2 = 0.f, a3 = 0.f;
        #pragma unroll
        for (int j = 0; j < OWN_G; j++) {
            float4 w = sb[j & (RING - 1)];
            if (j + RING < OWN_G) sb[j & (RING - 1)] = wp[(size_t)(PT_G + j + RING) * 512];
            DOT4(w, hvo, j * 4)
        }

        // ---- poll partner's h_{t-1} (proven R10 pattern) ----
        if (t > 0) {
            if (g == 0)
                while (__hip_atomic_load(par_flag, __ATOMIC_ACQUIRE,
                                         __HIP_MEMORY_SCOPE_AGENT) < t) {}
            __syncthreads();
        }

        // partner h at parity (t+1)&1 (zeroed for t=0)
        int rp = (t + 1) & 1;
        float hvp[2];
        #pragma unroll
        for (int j = 0; j < 2; j++)
            hvp[j] = __hip_atomic_load(hxc + rp * 256 + p0 + j * 64 + lane,
                                       __ATOMIC_RELAXED, __HIP_MEMORY_SCOPE_AGENT);

        // ---- phase B: partner-half dot (on-chip tiers, short) ----
        #pragma unroll
        for (int i = 0; i < KV / 4; i++) {
            float4 w = wr[i];
            DOT4(w, hvp, i * 4)
        }
        #pragma unroll
        for (int j = 0; j < KL_G; j++) {
            float4 w = wlds[j * 512 + g];
            DOT4(w, hvp, KV + j * 4)
        }
        DOT4(sbB[0], hvp, KV + 4 * KL_G)
        DOT4(sbB[1], hvp, KV + 4 * KL_G + 4)

        gates[g] = (a0 + a1) + (a2 + a3);
        __syncthreads();
        if (g < 128) {
            float gi = gates[g], gf = gates[128 + g], gg = gates[256 + g], go = gates[384 + g];
            float si = 1.f / (1.f + expf(-gi));
            float sf = 1.f / (1.f + expf(-gf));
            float so = 1.f / (1.f + expf(-go));
            c = sf * c + si * tanhf(gg);
            float h = so * tanhf(c);
            int u = unit0 + g;
            h_own[g] = h;                                // own half stays in LDS
            h_all[((size_t)b * SEQ + s) * 512 + dir * HDIM + u] = h;
            __hip_atomic_store(hxc + (t & 1) * 256 + u, h,
                               __ATOMIC_RELAXED, __HIP_MEMORY_SCOPE_AGENT);
        }
        __syncthreads();   // drains vmcnt/lds: h visible before flag, h_own before next phase A
        if (g == 0)
            __hip_atomic_store(own_flag, t + 1,
                               __ATOMIC_RELEASE, __HIP_MEMORY_SCOPE_AGENT);
    }
}

// ---------------- Kernel 5: output projection (feats) ----------------
__global__ void feats_kernel(const float* __restrict__ h_all, const float* __restrict__ w_out,
                             const float* __restrict__ b_out, float* __restrict__ feats) {
    int p = blockIdx.x;            // 8192
    int lane = threadIdx.x;        // 64
    const float* h = h_all + (size_t)p * 512;
    for (int f = 0; f < TAGS; f++) {
        float s = 0.f;
        const float* w = w_out + f * 512;
        #pragma unroll
        for (int k = 0; k < 512; k += 64) s += h[k + lane] * w[k + lane];
        #pragma unroll
        for (int off = 32; off; off >>= 1) s += __shfl_down(s, off);
        if (lane == 0) feats[(size_t)p * TAGS + f] = s + b_out[f];
    }
}

// ---------------- Kernel 6: Viterbi decode ----------------
__global__ void viterbi_kernel(const float* __restrict__ feats, const float* __restrict__ trans,
                               float* __restrict__ out) {
    int b = blockIdx.x;            // 32
    int t = threadIdx.x;           // 64
    __shared__ float fv[TAGS], fvn[TAGS], tr[TAGS * TAGS];
    __shared__ int bp[SEQ][TAGS];  // 12 KB

    for (int i = t; i < TAGS * TAGS; i += 64) tr[i] = trans[i];
    if (t < TAGS) fv[t] = (t == START_IDX) ? 0.f : NEGV;
    __syncthreads();

    const float* fb = feats + (size_t)b * SEQ * TAGS;
    for (int s = 0; s < SEQ; s++) {
        if (t < TAGS) {
            float best = fv[0] + tr[t * TAGS + 0];
            int bi = 0;
            #pragma unroll
            for (int prev = 1; prev < TAGS; prev++) {
                float v = fv[prev] + tr[t * TAGS + prev];
                if (v > best) { best = v; bi = prev; }   // first-index argmax
            }
            bp[s][t] = bi;
            fvn[t] = best + fb[s * TAGS + t];
        }
        __syncthreads();
        if (t < TAGS) fv[t] = fvn[t];
        __syncthreads();
    }

    if (t == 0) {
        float best = fv[0] + tr[STOP_IDX * TAGS + 0];
        int bi = 0;
        #pragma unroll
        for (int p = 1; p < TAGS; p++) {
            float v = fv[p] + tr[STOP_IDX * TAGS + p];
            if (v > best) { best = v; bi = p; }
        }
        out[b] = best;                                   // score
        float* path = out + BATCH + (size_t)b * SEQ;
        int tag = bi;
        path[SEQ - 1] = (float)tag;
        for (int s = SEQ - 1; s >= 1; s--) {
            tag = bp[s][tag];
            path[s - 1] = (float)tag;
        }
    }
}

// ---------------- Launch ----------------
extern "C" void kernel_launch(void* const* d_in, const int* in_sizes, int n_in,
                              void* d_out, int out_size, void* d_ws, size_t ws_size,
                              hipStream_t stream) {
    const int*   sent  = (const int*)d_in[0];
    const float* emb   = (const float*)d_in[1];
    const float* wih_f = (const float*)d_in[2];
    const float* whh_f = (const float*)d_in[3];
    const float* bih_f = (const float*)d_in[4];
    const float* bhh_f = (const float*)d_in[5];
    const float* wih_b = (const float*)d_in[6];
    const float* whh_b = (const float*)d_in[7];
    const float* bih_b = (const float*)d_in[8];
    const float* bhh_b = (const float*)d_in[9];
    const float* w_out = (const float*)d_in[10];
    const float* b_out = (const float*)d_in[11];
    const float* trans = (const float*)d_in[12];
    float* ws    = (float*)d_ws;
    float* xg    = ws + WS_XG;
    float* x     = ws + WS_X;
    float* wpack = ws + WS_WPACK;
    float* h_all = ws + WS_HALL;
    float* feats = ws + WS_FEATS;
    // sync state lives in the x region (dead after gemm_xg; zeroed after it)
    float* hx    = ws + WS_X;
    int*   flags = (int*)(ws + WS_X + 64 * 512);
    float* out   = (float*)d_out;

    gather_x<<<BATCH * SEQ, 64, 0, stream>>>(sent, emb, x);
    pack_whh<<<(2 * 2 * KSTR_G * 512 + 255) / 256, 256, 0, stream>>>(whh_f, whh_b, (float4*)wpack);
    gemm_xg<<<dim3(64, 16), 256, 0, stream>>>(x, wih_f, wih_b, bih_f, bhh_f, bih_b, bhh_b, xg);
    zero_sync<<<128, 256, 0, stream>>>(hx, flags);
    lstm_rec<<<128, 512, 0, stream>>>(xg, whh_f, whh_b, (const float4*)wpack, h_all, hx, flags);
    feats_kernel<<<BATCH * SEQ, 64, 0, stream>>>(h_all, w_out, b_out, feats);
    viterbi_kernel<<<BATCH, 64, 0, stream>>>(feats, trans, out);
}

// Round 18
// 1493.956 us; speedup vs baseline: 3.1654x; 1.0387x over previous
//
#include <hip/hip_runtime.h>
#include <math.h>

// Problem constants
#define BATCH 32
#define SEQ 256
#define EMBD 256
#define HDIM 256          // per-direction hidden
#define G4H 1024          // 4*H gates per direction
#define TAGS 12
#define START_IDX 10
#define STOP_IDX 11
#define NEGV -10000.0f

// lstm_rec: 2 WGs per (batch,dir) chain, 128 units each, 512 thr = 1 gate row
// per thread. Phase-split dot (R14, measured 1288->1192):
// own-half K streamed before the poll; partner-half on-chip after it.
// R16 change (ONE variable): block map half=blk>>6, chain=blk&63 puts both
// partners of a chain on the SAME XCD (blk c and c+64: c%8 == (c+64)%8 under
// round-robin dispatch) -> flag/h exchange at local-XCD latency instead of
// cross-die. Sync handshake byte-identical to R10/R13/R14.
#define KV 48            // partner VGPR-tier k-count
#define KL_G 18          // partner LDS-tier float4 groups
#define PT_G 2           // partner streamed tail groups
#define OWN_G 32         // own-half streamed groups
#define KSTR_G 34        // total streamed groups (= PT_G + OWN_G)
#define RING 8

// ---------------- Workspace layout (floats) ----------------
// xg     : [2][8192][1024]            = 16,777,216
// x      : [8192][256]                =  2,097,152   (dead after gemm_xg;
//           hx (64*512) + flags (128) live at its start during lstm_rec)
// wpack  : [2][2][34][512] float4     =    278,528 floats
// h_all  : [32][256][512]             =  4,194,304
// feats  : [32][256][12]              =     98,304
#define WS_XG    0
#define WS_X     16777216
#define WS_WPACK 18874368
#define WS_HALL  19234816
#define WS_FEATS 23429120

// broadcast h[k] from lane-distributed VGPR (compile-time lane index)
__device__ __forceinline__ float bcast(float v, int l) {
    return __int_as_float(__builtin_amdgcn_readlane(__float_as_int(v), l));
}

// ---------------- Kernel 1: gather embeddings ----------------
__global__ void gather_x(const int* __restrict__ sent, const float* __restrict__ emb,
                         float* __restrict__ x) {
    int m = blockIdx.x;            // 8192 positions (b*256+s)
    int lane = threadIdx.x;        // 64
    long long row = sent[m];
    float4 v = *(const float4*)(emb + row * EMBD + lane * 4);
    *(float4*)(x + (size_t)m * EMBD + lane * 4) = v;
}

// ---------------- Kernel 2: pack streamed weights ----------------
// For WG (dir,half): own base o0 = half*128, partner base p0 = 128-o0.
// Group j<2  -> partner tail k = p0 + 120 + 4j
// Group j>=2 -> own        k = o0 + 4*(j-2)
// pack[(((dir*2+half)*34)+j)*512 + g] = whh_dir[R(g,half)][k .. k+3]
__global__ void pack_whh(const float* __restrict__ whh_f, const float* __restrict__ whh_b,
                         float4* __restrict__ pack) {
    int idx = blockIdx.x * 256 + threadIdx.x;      // 2*2*34*512 = 69632
    if (idx >= 2 * 2 * KSTR_G * 512) return;
    int g = idx & 511;
    int r = idx >> 9;
    int j = r % KSTR_G; r /= KSTR_G;
    int half = r & 1, dir = r >> 1;
    int o0 = half * 128, p0 = 128 - o0;
    int R = (g >> 7) * 256 + o0 + (g & 127);
    int k = (j < PT_G) ? (p0 + KV + 4 * KL_G + 4 * j) : (o0 + 4 * (j - PT_G));
    const float* w = dir ? whh_b : whh_f;
    pack[idx] = *(const float4*)(w + (size_t)R * HDIM + k);
}

// ---------------- Kernel 3: xg GEMM  C[8192][2048] ----------------
__launch_bounds__(256)
__global__ void gemm_xg(const float* __restrict__ x,
                        const float* __restrict__ wih_f, const float* __restrict__ wih_b,
                        const float* __restrict__ bih_f, const float* __restrict__ bhh_f,
                        const float* __restrict__ bih_b, const float* __restrict__ bhh_b,
                        float* __restrict__ xg) {
    __shared__ __align__(16) float as[8][128];
    __shared__ __align__(16) float bs[8][128];
    int m0 = blockIdx.x * 128;     // 64 tiles
    int n0 = blockIdx.y * 128;     // 16 tiles
    int tid = threadIdx.x;
    int tx = tid & 15, ty = tid >> 4;
    int lr = tid >> 1;             // 0..127 tile row
    int lh = (tid & 1) * 4;        // k offset 0 or 4

    const float* arow = x + (size_t)(m0 + lr) * EMBD;
    const float* brow;
    {
        int n = n0 + lr;
        const float* w = (n < G4H) ? wih_f : wih_b;
        brow = w + (size_t)(n & 1023) * EMBD;
    }

    float acc[8][8];
    #pragma unroll
    for (int i = 0; i < 8; i++)
        #pragma unroll
        for (int j = 0; j < 8; j++) acc[i][j] = 0.f;

    for (int k0 = 0; k0 < EMBD; k0 += 8) {
        float4 av = *(const float4*)(arow + k0 + lh);
        float4 bv = *(const float4*)(brow + k0 + lh);
        __syncthreads();
        as[lh + 0][lr] = av.x; as[lh + 1][lr] = av.y; as[lh + 2][lr] = av.z; as[lh + 3][lr] = av.w;
        bs[lh + 0][lr] = bv.x; bs[lh + 1][lr] = bv.y; bs[lh + 2][lr] = bv.z; bs[lh + 3][lr] = bv.w;
        __syncthreads();
        #pragma unroll
        for (int kk = 0; kk < 8; kk++) {
            float4 a0 = *(const float4*)&as[kk][ty * 8];
            float4 a1 = *(const float4*)&as[kk][ty * 8 + 4];
            float4 b0 = *(const float4*)&bs[kk][tx * 8];
            float4 b1 = *(const float4*)&bs[kk][tx * 8 + 4];
            float a[8] = {a0.x, a0.y, a0.z, a0.w, a1.x, a1.y, a1.z, a1.w};
            float b[8] = {b0.x, b0.y, b0.z, b0.w, b1.x, b1.y, b1.z, b1.w};
            #pragma unroll
            for (int i = 0; i < 8; i++)
                #pragma unroll
                for (int j = 0; j < 8; j++) acc[i][j] += a[i] * b[j];
        }
    }

    int n = n0 + tx * 8;                 // tile stays within one dir (1024 % 128 == 0)
    int dir = n >> 10, g0 = n & 1023;
    const float* bih = dir ? bih_b : bih_f;
    const float* bhh = dir ? bhh_b : bhh_f;
    float bi[8], bh[8];
    #pragma unroll
    for (int j = 0; j < 8; j++) { bi[j] = bih[g0 + j]; bh[j] = bhh[g0 + j]; }
    float* ob = xg + (size_t)dir * 8192 * G4H;
    #pragma unroll
    for (int i = 0; i < 8; i++) {
        int m = m0 + ty * 8 + i;
        float v[8];
        #pragma unroll
        for (int j = 0; j < 8; j++) v[j] = (acc[i][j] + bi[j]) + bh[j];
        *(float4*)(ob + (size_t)m * G4H + g0)     = make_float4(v[0], v[1], v[2], v[3]);
        *(float4*)(ob + (size_t)m * G4H + g0 + 4) = make_float4(v[4], v[5], v[6], v[7]);
    }
}

// ---------------- Kernel 3b: zero sync state (every launch, after gemm) ----
__global__ void zero_sync(float* __restrict__ hx, int* __restrict__ flags) {
    int i = blockIdx.x * 256 + threadIdx.x;
    if (i < 64 * 512) hx[i] = 0.f;
    if (i < 128) flags[i] = 0;
}

// ---------------- Kernel 4: LSTM recurrence (phase-split, same-XCD pairs) --
#define DOT4(W, HV, KL)                                              \
    a0 += (W).x * bcast(HV[((KL) + 0) >> 6], ((KL) + 0) & 63);       \
    a1 += (W).y * bcast(HV[((KL) + 1) >> 6], ((KL) + 1) & 63);       \
    a2 += (W).z * bcast(HV[((KL) + 2) >> 6], ((KL) + 2) & 63);       \
    a3 += (W).w * bcast(HV[((KL) + 3) >> 6], ((KL) + 3) & 63);

__launch_bounds__(512)
__global__ void lstm_rec(const float* __restrict__ xg,
                         const float* __restrict__ whh_f, const float* __restrict__ whh_b,
                         const float4* __restrict__ wpack,
                         float* __restrict__ h_all,
                         float* __restrict__ hx, int* __restrict__ flags) {
    int blk = blockIdx.x;            // 128
    int half = blk >> 6;             // R16: partners blk c / c+64 -> SAME XCD (c%8)
    int chain = blk & 63;            // 64
    int dir = chain & 1, b = chain >> 1;
    int g = threadIdx.x;             // 0..511
    int lane = g & 63;
    int unit0 = half * 128;          // own base o0
    int p0 = 128 - unit0;            // partner base
    int R = (g >> 7) * 256 + unit0 + (g & 127);    // global gate row

    const float* whh = dir ? whh_b : whh_f;
    const float* wrow = whh + (size_t)R * HDIM;
    const float4* wp = wpack + (size_t)(dir * 2 + half) * KSTR_G * 512 + g;
    const float* xgb = xg + (size_t)dir * 8192 * G4H + (size_t)b * SEQ * G4H + R;
    float* hxc = hx + chain * 512;                 // [2 parity][256 units]
    int* own_flag = flags + chain * 2 + half;
    int* par_flag = flags + chain * 2 + (1 - half);

    __shared__ __align__(16) float4 wlds[KL_G * 512];     // 147,456 B
    __shared__ float gates[512];                          //   2,048 B
    __shared__ float h_own[128];                          //     512 B

    // one-time stages: partner-half on-chip tiers
    #pragma unroll
    for (int j = 0; j < KL_G; j++)
        wlds[j * 512 + g] = *(const float4*)(wrow + p0 + KV + j * 4);
    float4 wr[KV / 4];
    #pragma unroll
    for (int i = 0; i < KV / 4; i++)
        wr[i] = *(const float4*)(wrow + p0 + i * 4);

    float c = 0.f;
    if (g < 128) h_own[g] = 0.f;
    __syncthreads();

    for (int t = 0; t < SEQ; t++) {
        int s = dir ? (SEQ - 1 - t) : t;

        // pre-issue all h-independent long-latency loads
        float xval = xgb[(size_t)s * G4H];
        float4 sbB[2];                                   // partner streamed tail
        sbB[0] = wp[0 * 512]; sbB[1] = wp[1 * 512];
        float4 sb[RING];                                 // own ring, groups 2..9
        #pragma unroll
        for (int p = 0; p < RING; p++) sb[p] = wp[(size_t)(PT_G + p) * 512];

        // ---- phase A: own-half dot (h from LDS, no wait) ----
        float hvo[2];
        #pragma unroll
        for (int j = 0; j < 2; j++) hvo[j] = h_own[j * 64 + lane];

        float a0 = xval, a1 = 0.f, a2 = 0.f, a3 = 0.f;
        #pragma unroll
        for (int j = 0; j < OWN_G; j++) {
            float4 w = sb[j & (RING - 1)];
            if (j + RING < OWN_G) sb[j & (RING - 1)] = wp[(size_t)(PT_G + j + RING) * 512];
            DOT4(w, hvo, j * 4)
        }

        // ---- poll partner's h_{t-1} (proven R10 pattern) ----
        if (t > 0) {
            if (g == 0)
                while (__hip_atomic_load(par_flag, __ATOMIC_ACQUIRE,
                                         __HIP_MEMORY_SCOPE_AGENT) < t) {}
            __syncthreads();
        }

        // partner h at parity (t+1)&1 (zeroed for t=0)
        int rp = (t + 1) & 1;
        float hvp[2];
        #pragma unroll
        for (int j = 0; j < 2; j++)
            hvp[j] = __hip_atomic_load(hxc + rp * 256 + p0 + j * 64 + lane,
                                       __ATOMIC_RELAXED, __HIP_MEMORY_SCOPE_AGENT);

        // ---- phase B: partner-half dot (on-chip tiers, short) ----
        #pragma unroll
        for (int i = 0; i < KV / 4; i++) {
            float4 w = wr[i];
            DOT4(w, hvp, i * 4)
        }
        #pragma unroll
        for (int j = 0; j < KL_G; j++) {
            float4 w = wlds[j * 512 + g];
            DOT4(w, hvp, KV + j * 4)
        }
        DOT4(sbB[0], hvp, KV + 4 * KL_G)
        DOT4(sbB[1], hvp, KV + 4 * KL_G + 4)

        gates[g] = (a0 + a1) + (a2 + a3);
        __syncthreads();
        if (g < 128) {
            float gi = gates[g], gf = gates[128 + g], gg = gates[256 + g], go = gates[384 + g];
            float si = 1.f / (1.f + expf(-gi));
            float sf = 1.f / (1.f + expf(-gf));
            float so = 1.f / (1.f + expf(-go));
            c = sf * c + si * tanhf(gg);
            float h = so * tanhf(c);
            int u = unit0 + g;
            h_own[g] = h;                                // own half stays in LDS
            h_all[((size_t)b * SEQ + s) * 512 + dir * HDIM + u] = h;
            __hip_atomic_store(hxc + (t & 1) * 256 + u, h,
                               __ATOMIC_RELAXED, __HIP_MEMORY_SCOPE_AGENT);
        }
        __syncthreads();   // drains vmcnt/lds: h visible before flag, h_own before next phase A
        if (g == 0)
            __hip_atomic_store(own_flag, t + 1,
                               __ATOMIC_RELEASE, __HIP_MEMORY_SCOPE_AGENT);
    }
}

// ---------------- Kernel 5: output projection (feats) ----------------
__global__ void feats_kernel(const float* __restrict__ h_all, const float* __restrict__ w_out,
                             const float* __restrict__ b_out, float* __restrict__ feats) {
    int p = blockIdx.x;            // 8192
    int lane = threadIdx.x;        // 64
    const float* h = h_all + (size_t)p * 512;
    for (int f = 0; f < TAGS; f++) {
        float s = 0.f;
        const float* w = w_out + f * 512;
        #pragma unroll
        for (int k = 0; k < 512; k += 64) s += h[k + lane] * w[k + lane];
        #pragma unroll
        for (int off = 32; off; off >>= 1) s += __shfl_down(s, off);
        if (lane == 0) feats[(size_t)p * TAGS + f] = s + b_out[f];
    }
}

// ---------------- Kernel 6: Viterbi decode ----------------
__global__ void viterbi_kernel(const float* __restrict__ feats, const float* __restrict__ trans,
                               float* __restrict__ out) {
    int b = blockIdx.x;            // 32
    int t = threadIdx.x;           // 64
    __shared__ float fv[TAGS], fvn[TAGS], tr[TAGS * TAGS];
    __shared__ int bp[SEQ][TAGS];  // 12 KB

    for (int i = t; i < TAGS * TAGS; i += 64) tr[i] = trans[i];
    if (t < TAGS) fv[t] = (t == START_IDX) ? 0.f : NEGV;
    __syncthreads();

    const float* fb = feats + (size_t)b * SEQ * TAGS;
    for (int s = 0; s < SEQ; s++) {
        if (t < TAGS) {
            float best = fv[0] + tr[t * TAGS + 0];
            int bi = 0;
            #pragma unroll
            for (int prev = 1; prev < TAGS; prev++) {
                float v = fv[prev] + tr[t * TAGS + prev];
                if (v > best) { best = v; bi = prev; }   // first-index argmax
            }
            bp[s][t] = bi;
            fvn[t] = best + fb[s * TAGS + t];
        }
        __syncthreads();
        if (t < TAGS) fv[t] = fvn[t];
        __syncthreads();
    }

    if (t == 0) {
        float best = fv[0] + tr[STOP_IDX * TAGS + 0];
        int bi = 0;
        #pragma unroll
        for (int p = 1; p < TAGS; p++) {
            float v = fv[p] + tr[STOP_IDX * TAGS + p];
            if (v > best) { best = v; bi = p; }
        }
        out[b] = best;                                   // score
        float* path = out + BATCH + (size_t)b * SEQ;
        int tag = bi;
        path[SEQ - 1] = (float)tag;
        for (int s = SEQ - 1; s >= 1; s--) {
            tag = bp[s][tag];
            path[s - 1] = (float)tag;
        }
    }
}

// ---------------- Launch ----------------
extern "C" void kernel_launch(void* const* d_in, const int* in_sizes, int n_in,
                              void* d_out, int out_size, void* d_ws, size_t ws_size,
                              hipStream_t stream) {
    const int*   sent  = (const int*)d_in[0];
    const float* emb   = (const float*)d_in[1];
    const float* wih_f = (const float*)d_in[2];
    const float* whh_f = (const float*)d_in[3];
    const float* bih_f = (const float*)d_in[4];
    const float* bhh_f = (const float*)d_in[5];
    const float* wih_b = (const float*)d_in[6];
    const float* whh_b = (const float*)d_in[7];
    const float* bih_b = (const float*)d_in[8];
    const float* bhh_b = (const float*)d_in[9];
    const float* w_out = (const float*)d_in[10];
    const float* b_out = (const float*)d_in[11];
    const float* trans = (const float*)d_in[12];
    float* ws    = (float*)d_ws;
    float* xg    = ws + WS_XG;
    float* x     = ws + WS_X;
    float* wpack = ws + WS_WPACK;
    float* h_all = ws + WS_HALL;
    float* feats = ws + WS_FEATS;
    // sync state lives in the x region (dead after gemm_xg; zeroed after it)
    float* hx    = ws + WS_X;
    int*   flags = (int*)(ws + WS_X + 64 * 512);
    float* out   = (float*)d_out;

    gather_x<<<BATCH * SEQ, 64, 0, stream>>>(sent, emb, x);
    pack_whh<<<(2 * 2 * KSTR_G * 512 + 255) / 256, 256, 0, stream>>>(whh_f, whh_b, (float4*)wpack);
    gemm_xg<<<dim3(64, 16), 256, 0, stream>>>(x, wih_f, wih_b, bih_f, bhh_f, bih_b, bhh_b, xg);
    zero_sync<<<128, 256, 0, stream>>>(hx, flags);
    lstm_rec<<<128, 512, 0, stream>>>(xg, whh_f, whh_b, (const float4*)wpack, h_all, hx, flags);
    feats_kernel<<<BATCH * SEQ, 64, 0, stream>>>(h_all, w_out, b_out, feats);
    viterbi_kernel<<<BATCH, 64, 0, stream>>>(feats, trans, out);
}